// Round 13
// baseline (151.128 us; speedup 1.0000x reference)
//
#include <hip/hip_runtime.h>

#define NN 50000
#define NC 256
#define DD 64
#define HH 128
#define EVV 800000
#define EVC 400000
#define NE 1200000
#define NB 196              // coarse buckets of 256 vertices (d>>8)
#define BCAP 8192           // records per bucket region; mean 6122, +26 sigma
#define MLPV_B 3125         // ceil(NN/16)
#define MLPC_B 16           // NC/16
#define MLP_B (MLPV_B + MLPC_B)   // 3141 (16-row blocks)
#define FILL_EPB 4096       // 2x r12: halves the per-address gcur atomic chains
#define FILL_B 293          // ceil(NE/4096)
#define K1_B (FILL_B * 12)  // period-12 interleave: 1 fill + 11 mlp
#define GAT_B (NB * 8)      // 1568 blocks: 8 sub-blocks x 32 vertices / bucket
#define VCAP 64             // slots per vertex; Poisson(24), P(>64) ~ 1e-11

__device__ __forceinline__ unsigned short f2bf(float x) {
  unsigned u = __float_as_uint(x);
  u = (u + 0x7fffu + ((u >> 16) & 1u)) >> 16;  // round-to-nearest-even
  return (unsigned short)u;
}

// LDS overlay: mlp (12 KB) and fill (~20.7 KB) never coexist in a block.
union SMem {
  struct {
    float xs[4][64][4];    // 4 KB
    float hs[4][128][4];   // 8 KB
  } m;
  struct {
    int cnt[NB];
    int off[NB];
    int gbase[NB];
    int sa[256], sb[256];
    unsigned int stage[FILL_EPB];  // 16 KB
  } f;
};

// ---------------------------------------------------------------------------
// MLP for 16 rows (4 waves x 4 rows): table[r] = bf16(relu(X@W1+b1)@W2+b2).
// Inner-loop reads are wave-uniform b128 broadcasts (r12 form, unchanged).
// ---------------------------------------------------------------------------
__device__ __forceinline__ void mlp16(
    const float* __restrict__ X, const float* __restrict__ W1,
    const float* __restrict__ b1, const float* __restrict__ W2,
    const float* __restrict__ b2, unsigned short* __restrict__ Y, int blk,
    int nrows, float (*xs)[64][4], float (*hs)[128][4]) {
  const int wave = threadIdx.x >> 6;
  const int lane = threadIdx.x & 63;
  const int row0 = (blk * 4 + wave) * 4;

  {
    float4 a;
    a.x = (row0 + 0 < nrows) ? X[(row0 + 0) * DD + lane] : 0.f;
    a.y = (row0 + 1 < nrows) ? X[(row0 + 1) * DD + lane] : 0.f;
    a.z = (row0 + 2 < nrows) ? X[(row0 + 2) * DD + lane] : 0.f;
    a.w = (row0 + 3 < nrows) ? X[(row0 + 3) * DD + lane] : 0.f;
    *(float4*)&xs[wave][lane][0] = a;
  }
  __syncthreads();

  const float bias0 = b1[lane];
  const float bias1 = b1[lane + 64];
  float h0[4], h1[4];
#pragma unroll
  for (int r = 0; r < 4; ++r) { h0[r] = bias0; h1[r] = bias1; }

#pragma unroll 8
  for (int k = 0; k < 64; ++k) {
    const float4 xa = *(const float4*)&xs[wave][k][0];  // b128 broadcast
    const float wa = W1[k * HH + lane];                 // coalesced, L1-hot
    const float wb = W1[k * HH + 64 + lane];
    h0[0] = fmaf(xa.x, wa, h0[0]); h1[0] = fmaf(xa.x, wb, h1[0]);
    h0[1] = fmaf(xa.y, wa, h0[1]); h1[1] = fmaf(xa.y, wb, h1[1]);
    h0[2] = fmaf(xa.z, wa, h0[2]); h1[2] = fmaf(xa.z, wb, h1[2]);
    h0[3] = fmaf(xa.w, wa, h0[3]); h1[3] = fmaf(xa.w, wb, h1[3]);
  }
  *(float4*)&hs[wave][lane][0] =
      make_float4(fmaxf(h0[0], 0.f), fmaxf(h0[1], 0.f), fmaxf(h0[2], 0.f),
                  fmaxf(h0[3], 0.f));
  *(float4*)&hs[wave][lane + 64][0] =
      make_float4(fmaxf(h1[0], 0.f), fmaxf(h1[1], 0.f), fmaxf(h1[2], 0.f),
                  fmaxf(h1[3], 0.f));
  __syncthreads();

  const float bias2 = b2[lane];
  float a[4];
#pragma unroll
  for (int r = 0; r < 4; ++r) a[r] = bias2;

#pragma unroll 8
  for (int j = 0; j < HH; ++j) {
    const float4 ha = *(const float4*)&hs[wave][j][0];  // b128 broadcast
    const float w = W2[j * DD + lane];                  // coalesced, L1-hot
    a[0] = fmaf(ha.x, w, a[0]);
    a[1] = fmaf(ha.y, w, a[1]);
    a[2] = fmaf(ha.z, w, a[2]);
    a[3] = fmaf(ha.w, w, a[3]);
  }
#pragma unroll
  for (int r = 0; r < 4; ++r)
    if (row0 + r < nrows) Y[(row0 + r) * DD + lane] = f2bf(a[r]);
}

// ---------------------------------------------------------------------------
// Fill branch (4096 edges/block): block-local counting sort into NB coarse
// buckets; ONE global atomic per (block,bucket) reserves a run at bucket*BCAP
// -> per-address reservation chains now 293-long (was 586).
// Record = (d<<16)|s.
// ---------------------------------------------------------------------------
__device__ __forceinline__ void fill_block(
    const int* __restrict__ src_vv, const int* __restrict__ dst_vv,
    const int* __restrict__ src_vc, const int* __restrict__ dst_vc,
    int* __restrict__ gcur, unsigned int* __restrict__ records, int blk,
    SMem* sm) {
  const int t = threadIdx.x;
  const int base = blk * FILL_EPB;
  if (t < NB) sm->f.cnt[t] = 0;
  __syncthreads();

  unsigned int rec[16];
  int rk[16];
#pragma unroll
  for (int r = 0; r < 16; ++r) {
    const int e = base + r * 256 + t;
    rk[r] = -1;
    if (e < NE) {
      int s, d;
      if (e < EVV) {
        s = src_vv[e];
        d = dst_vv[e];
      } else {
        s = NN + src_vc[e - EVV];
        d = dst_vc[e - EVV];
      }
      rec[r] = ((unsigned int)d << 16) | (unsigned int)s;
      rk[r] = atomicAdd(&sm->f.cnt[d >> 8], 1);
    }
  }
  __syncthreads();

  const int val = (t < NB) ? sm->f.cnt[t] : 0;
  sm->f.sa[t] = val;
  __syncthreads();
  int* s = sm->f.sa;
  int* d = sm->f.sb;
  for (int o = 1; o < 256; o <<= 1) {
    d[t] = s[t] + ((t >= o) ? s[t - o] : 0);
    __syncthreads();
    int* tmp = s; s = d; d = tmp;
  }
  if (t < NB) {
    sm->f.off[t] = s[t] - val;
    sm->f.gbase[t] = t * BCAP + ((val > 0) ? atomicAdd(&gcur[t], val) : 0);
  }
  __syncthreads();

#pragma unroll
  for (int r = 0; r < 16; ++r)
    if (rk[r] >= 0) sm->f.stage[sm->f.off[rec[r] >> 24] + rk[r]] = rec[r];
  __syncthreads();

  const int total = (NE - base < FILL_EPB) ? (NE - base) : FILL_EPB;
  for (int i = t; i < total; i += 256) {
    const unsigned int u = sm->f.stage[i];
    const int b2 = u >> 24;  // = d >> 8
    records[sm->f.gbase[b2] + (i - sm->f.off[b2])] = u;
  }
}

// ---------------------------------------------------------------------------
// K1 fused, INTERLEAVED period-12: {1 fill block, 11 mlp blocks}.
// ---------------------------------------------------------------------------
__global__ __launch_bounds__(256) void k1_kernel(
    const float* __restrict__ x_v, const float* __restrict__ x_c,
    const float* __restrict__ W1v, const float* __restrict__ b1v,
    const float* __restrict__ W2v, const float* __restrict__ b2v,
    const float* __restrict__ W1c, const float* __restrict__ b1c,
    const float* __restrict__ W2c, const float* __restrict__ b2c,
    const int* __restrict__ src_vv, const int* __restrict__ dst_vv,
    const int* __restrict__ src_vc, const int* __restrict__ dst_vc,
    unsigned short* __restrict__ table, int* __restrict__ gcur,
    unsigned int* __restrict__ records) {
  __shared__ SMem sm;
  const int q = blockIdx.x / 12;
  const int r = blockIdx.x % 12;
  if (r == 0) {
    fill_block(src_vv, dst_vv, src_vc, dst_vc, gcur, records, q, &sm);
  } else {
    const int mb = q * 11 + (r - 1);
    if (mb >= MLP_B) return;
    if (mb < MLPV_B)
      mlp16(x_v, W1v, b1v, W2v, b2v, table, mb, NN, sm.m.xs, sm.m.hs);
    else
      mlp16(x_c, W1c, b1c, W2c, b2c, table + (size_t)NN * DD, mb - MLPV_B, NC,
            sm.m.xs, sm.m.hs);
  }
}

// ---------------------------------------------------------------------------
// Gather: 512-thread blocks, 32 vertices, 16 lanes/vertex (uint2 row chunks).
// Wave demand ~49/CU keeps the 32-wave budget (and MSHRs) saturated through
// the tail. One placement pass -> fixed 64-slot per-vertex LDS lists; then
// accumulate 8 rows in flight + x_v + relu.
// ---------------------------------------------------------------------------
__device__ __forceinline__ void acc4(float* a, const uint2 t) {
  a[0] += __uint_as_float(t.x << 16);
  a[1] += __uint_as_float(t.x & 0xffff0000u);
  a[2] += __uint_as_float(t.y << 16);
  a[3] += __uint_as_float(t.y & 0xffff0000u);
}

__device__ __forceinline__ void place(unsigned int u, int sub, int* c1,
                                      unsigned short* slots) {
  const int dd = u >> 16;
  if (((dd >> 5) & 7) == sub) {
    const int lv = dd & 31;
    const int pos = atomicAdd(&c1[lv], 1);
    if (pos < VCAP) slots[lv * VCAP + pos] = (unsigned short)(u & 0xffffu);
  }
}

__global__ __launch_bounds__(512) void gather_kernel(
    const uint2* __restrict__ table2, const unsigned int* __restrict__ records,
    const int* __restrict__ gcur, const float4* __restrict__ xv4,
    float4* __restrict__ out4) {
  __shared__ int c1[32];
  __shared__ unsigned short slots[32 * VCAP];  // 4 KB
  const int t = threadIdx.x;
  const int bucket = blockIdx.x >> 3;
  const int sub = blockIdx.x & 7;
  const int start = bucket * BCAP;
  const int nrec = gcur[bucket];

  // early x_v prefetch (independent of the record scan)
  const int g = t >> 4;   // vertex within sub-block (0..31)
  const int c = t & 15;   // float4 chunk (0..15)
  const int v = bucket * 256 + sub * 32 + g;
  const size_t ob = (size_t)v * 16 + c;
  float4 x0 = {0.f, 0.f, 0.f, 0.f};
  if (v < NN) x0 = xv4[ob];

  if (t < 32) c1[t] = 0;
  __syncthreads();

  // single placement pass, uint4-vectorized (records base is 32KB-aligned)
  const uint4* rec4 = (const uint4*)(records + start);
  const int nfull = nrec >> 2;
  for (int q = t; q < nfull; q += 512) {
    const uint4 u = rec4[q];
    place(u.x, sub, c1, slots);
    place(u.y, sub, c1, slots);
    place(u.z, sub, c1, slots);
    place(u.w, sub, c1, slots);
  }
  for (int j = (nfull << 2) + t; j < nrec; j += 512)
    place(records[start + j], sub, c1, slots);
  __syncthreads();

  if (v >= NN) return;
  int n = c1[g];
  n = (n > VCAP) ? VCAP : n;
  const unsigned short* sl = slots + g * VCAP;

  float a[4] = {0.f, 0.f, 0.f, 0.f};

  int i = 0;
  for (; i + 8 <= n; i += 8) {
    const int e0 = sl[i + 0];
    const int e1 = sl[i + 1];
    const int e2 = sl[i + 2];
    const int e3 = sl[i + 3];
    const int e4 = sl[i + 4];
    const int e5 = sl[i + 5];
    const int e6 = sl[i + 6];
    const int e7 = sl[i + 7];
    const uint2 t0 = table2[(size_t)e0 * 16 + c];  // 128 B/row, coalesced
    const uint2 t1 = table2[(size_t)e1 * 16 + c];
    const uint2 t2 = table2[(size_t)e2 * 16 + c];
    const uint2 t3 = table2[(size_t)e3 * 16 + c];
    const uint2 t4 = table2[(size_t)e4 * 16 + c];
    const uint2 t5 = table2[(size_t)e5 * 16 + c];
    const uint2 t6 = table2[(size_t)e6 * 16 + c];
    const uint2 t7 = table2[(size_t)e7 * 16 + c];
    acc4(a, t0); acc4(a, t1); acc4(a, t2); acc4(a, t3);
    acc4(a, t4); acc4(a, t5); acc4(a, t6); acc4(a, t7);
  }
  for (; i + 4 <= n; i += 4) {
    const int e0 = sl[i + 0];
    const int e1 = sl[i + 1];
    const int e2 = sl[i + 2];
    const int e3 = sl[i + 3];
    const uint2 t0 = table2[(size_t)e0 * 16 + c];
    const uint2 t1 = table2[(size_t)e1 * 16 + c];
    const uint2 t2 = table2[(size_t)e2 * 16 + c];
    const uint2 t3 = table2[(size_t)e3 * 16 + c];
    acc4(a, t0); acc4(a, t1); acc4(a, t2); acc4(a, t3);
  }
  for (; i < n; ++i) acc4(a, table2[(size_t)sl[i] * 16 + c]);

  float4 o;
  o.x = fmaxf(x0.x + a[0], 0.f);
  o.y = fmaxf(x0.y + a[1], 0.f);
  o.z = fmaxf(x0.z + a[2], 0.f);
  o.w = fmaxf(x0.w + a[3], 0.f);
  out4[ob] = o;
}

extern "C" void kernel_launch(void* const* d_in, const int* in_sizes, int n_in,
                              void* d_out, int out_size, void* d_ws,
                              size_t ws_size, hipStream_t stream) {
  const float* x_v = (const float*)d_in[0];
  const float* x_c = (const float*)d_in[1];
  const float* W1v = (const float*)d_in[2];
  const float* b1v = (const float*)d_in[3];
  const float* W2v = (const float*)d_in[4];
  const float* b2v = (const float*)d_in[5];
  const float* W1c = (const float*)d_in[6];
  const float* b1c = (const float*)d_in[7];
  const float* W2c = (const float*)d_in[8];
  const float* b2c = (const float*)d_in[9];
  const int* src_vv = (const int*)d_in[10];
  const int* dst_vv = (const int*)d_in[11];
  const int* src_vc = (const int*)d_in[12];
  const int* dst_vc = (const int*)d_in[13];
  float* out = (float*)d_out;

  // workspace: table(bf16) 6.43 MB | records 6.42 MB | gcur 784 B
  char* p = (char*)d_ws;
  unsigned short* table = (unsigned short*)p;
  p += (size_t)(NN + NC) * DD * sizeof(unsigned short);
  unsigned int* records = (unsigned int*)p;
  p += (size_t)NB * BCAP * sizeof(unsigned int);
  int* gcur = (int*)p;

  hipMemsetAsync(gcur, 0, NB * sizeof(int), stream);

  k1_kernel<<<K1_B, 256, 0, stream>>>(x_v, x_c, W1v, b1v, W2v, b2v, W1c, b1c,
                                      W2c, b2c, src_vv, dst_vv, src_vc, dst_vc,
                                      table, gcur, records);

  gather_kernel<<<GAT_B, 512, 0, stream>>>((const uint2*)table, records, gcur,
                                           (const float4*)x_v, (float4*)out);
}

// Round 14
// 150.850 us; speedup vs baseline: 1.0018x; 1.0018x over previous
//
#include <hip/hip_runtime.h>

#define NN 50000
#define NC 256
#define DD 64
#define HH 128
#define EVV 800000
#define EVC 400000
#define NE 1200000
#define NB 196              // coarse buckets of 256 vertices (d>>8)
#define BCAP 8192           // records per bucket region; mean 6122, +26 sigma
#define MLPV_B 3125         // ceil(NN/16)
#define MLPC_B 16           // NC/16
#define MLP_B (MLPV_B + MLPC_B)   // 3141 (16-row blocks)
#define FILL_EPB 2048
#define FILL_B 586          // ceil(NE/2048)
#define K1_B (FILL_B * 7)   // period-7 interleave: 1 fill + 6 mlp per septet
#define GAT_B (NB * 8)      // 1568 blocks: 8 sub-blocks x 32 vertices / bucket
#define VCAP 64             // slots per vertex; Poisson(24), P(>64) ~ 1e-11

__device__ __forceinline__ unsigned short f2bf(float x) {
  unsigned u = __float_as_uint(x);
  u = (u + 0x7fffu + ((u >> 16) & 1u)) >> 16;  // round-to-nearest-even
  return (unsigned short)u;
}

// LDS overlay: mlp (12 KB, 16-row fp32 tiles) and fill (~12.6 KB) never coexist.
union SMem {
  struct {
    float xs[4][64][4];    // 4 KB
    float hs[4][128][4];   // 8 KB
  } m;
  struct {
    int cnt[NB];
    int off[NB];
    int gbase[NB];
    int sa[256], sb[256];
    unsigned int stage[FILL_EPB];  // 8 KB
  } f;
};

// ---------------------------------------------------------------------------
// MLP for 16 rows (4 waves x 4 rows): table[r] = bf16(relu(X@W1+b1)@W2+b2).
// BARRIER-FREE: xs[wave]/hs[wave] are wave-private (written and read only by
// this wave's lanes); in-wave LDS ordering via compiler lgkmcnt waits is
// sufficient. Removing the 2 __syncthreads decouples the 4 waves so staging
// latency and W-load drains overlap across waves instead of serializing.
// ---------------------------------------------------------------------------
__device__ __forceinline__ void mlp16(
    const float* __restrict__ X, const float* __restrict__ W1,
    const float* __restrict__ b1, const float* __restrict__ W2,
    const float* __restrict__ b2, unsigned short* __restrict__ Y, int blk,
    int nrows, float (*xs)[64][4], float (*hs)[128][4]) {
  const int wave = threadIdx.x >> 6;
  const int lane = threadIdx.x & 63;
  const int row0 = (blk * 4 + wave) * 4;

  {
    float4 a;
    a.x = (row0 + 0 < nrows) ? X[(row0 + 0) * DD + lane] : 0.f;
    a.y = (row0 + 1 < nrows) ? X[(row0 + 1) * DD + lane] : 0.f;
    a.z = (row0 + 2 < nrows) ? X[(row0 + 2) * DD + lane] : 0.f;
    a.w = (row0 + 3 < nrows) ? X[(row0 + 3) * DD + lane] : 0.f;
    *(float4*)&xs[wave][lane][0] = a;
  }
  // no __syncthreads: wave-private tile, lgkmcnt ordering suffices

  const float bias0 = b1[lane];
  const float bias1 = b1[lane + 64];
  float h0[4], h1[4];
#pragma unroll
  for (int r = 0; r < 4; ++r) { h0[r] = bias0; h1[r] = bias1; }

#pragma unroll 8
  for (int k = 0; k < 64; ++k) {
    const float4 xa = *(const float4*)&xs[wave][k][0];  // b128 broadcast
    const float wa = W1[k * HH + lane];                 // coalesced, L1-hot
    const float wb = W1[k * HH + 64 + lane];
    h0[0] = fmaf(xa.x, wa, h0[0]); h1[0] = fmaf(xa.x, wb, h1[0]);
    h0[1] = fmaf(xa.y, wa, h0[1]); h1[1] = fmaf(xa.y, wb, h1[1]);
    h0[2] = fmaf(xa.z, wa, h0[2]); h1[2] = fmaf(xa.z, wb, h1[2]);
    h0[3] = fmaf(xa.w, wa, h0[3]); h1[3] = fmaf(xa.w, wb, h1[3]);
  }
  *(float4*)&hs[wave][lane][0] =
      make_float4(fmaxf(h0[0], 0.f), fmaxf(h0[1], 0.f), fmaxf(h0[2], 0.f),
                  fmaxf(h0[3], 0.f));
  *(float4*)&hs[wave][lane + 64][0] =
      make_float4(fmaxf(h1[0], 0.f), fmaxf(h1[1], 0.f), fmaxf(h1[2], 0.f),
                  fmaxf(h1[3], 0.f));
  // no __syncthreads: wave-private tile

  const float bias2 = b2[lane];
  float a[4];
#pragma unroll
  for (int r = 0; r < 4; ++r) a[r] = bias2;

#pragma unroll 8
  for (int j = 0; j < HH; ++j) {
    const float4 ha = *(const float4*)&hs[wave][j][0];  // b128 broadcast
    const float w = W2[j * DD + lane];                  // coalesced, L1-hot
    a[0] = fmaf(ha.x, w, a[0]);
    a[1] = fmaf(ha.y, w, a[1]);
    a[2] = fmaf(ha.z, w, a[2]);
    a[3] = fmaf(ha.w, w, a[3]);
  }
#pragma unroll
  for (int r = 0; r < 4; ++r)
    if (row0 + r < nrows) Y[(row0 + r) * DD + lane] = f2bf(a[r]);
}

// ---------------------------------------------------------------------------
// Fill branch: block-local counting sort into NB coarse buckets; ONE global
// atomic per (block,bucket) reserves a run at bucket*BCAP; bucket-ordered
// copy-out -> coalesced runs. Record = (d<<16)|s.
// ---------------------------------------------------------------------------
__device__ __forceinline__ void fill_block(
    const int* __restrict__ src_vv, const int* __restrict__ dst_vv,
    const int* __restrict__ src_vc, const int* __restrict__ dst_vc,
    int* __restrict__ gcur, unsigned int* __restrict__ records, int blk,
    SMem* sm) {
  const int t = threadIdx.x;
  const int base = blk * FILL_EPB;
  if (t < NB) sm->f.cnt[t] = 0;
  __syncthreads();

  unsigned int rec[8];
  int rk[8];
#pragma unroll
  for (int r = 0; r < 8; ++r) {
    const int e = base + r * 256 + t;
    rk[r] = -1;
    if (e < NE) {
      int s, d;
      if (e < EVV) {
        s = src_vv[e];
        d = dst_vv[e];
      } else {
        s = NN + src_vc[e - EVV];
        d = dst_vc[e - EVV];
      }
      rec[r] = ((unsigned int)d << 16) | (unsigned int)s;
      rk[r] = atomicAdd(&sm->f.cnt[d >> 8], 1);
    }
  }
  __syncthreads();

  const int val = (t < NB) ? sm->f.cnt[t] : 0;
  sm->f.sa[t] = val;
  __syncthreads();
  int* s = sm->f.sa;
  int* d = sm->f.sb;
  for (int o = 1; o < 256; o <<= 1) {
    d[t] = s[t] + ((t >= o) ? s[t - o] : 0);
    __syncthreads();
    int* tmp = s; s = d; d = tmp;
  }
  if (t < NB) {
    sm->f.off[t] = s[t] - val;
    sm->f.gbase[t] = t * BCAP + ((val > 0) ? atomicAdd(&gcur[t], val) : 0);
  }
  __syncthreads();

#pragma unroll
  for (int r = 0; r < 8; ++r)
    if (rk[r] >= 0) sm->f.stage[sm->f.off[rec[r] >> 24] + rk[r]] = rec[r];
  __syncthreads();

  const int total = (NE - base < FILL_EPB) ? (NE - base) : FILL_EPB;
  for (int i = t; i < total; i += 256) {
    const unsigned int u = sm->f.stage[i];
    const int b2 = u >> 24;  // = d >> 8
    records[sm->f.gbase[b2] + (i - sm->f.off[b2])] = u;
  }
}

// ---------------------------------------------------------------------------
// K1 fused, INTERLEAVED period-7: septet q = {1 fill block, 6 mlp blocks}.
// ---------------------------------------------------------------------------
__global__ __launch_bounds__(256) void k1_kernel(
    const float* __restrict__ x_v, const float* __restrict__ x_c,
    const float* __restrict__ W1v, const float* __restrict__ b1v,
    const float* __restrict__ W2v, const float* __restrict__ b2v,
    const float* __restrict__ W1c, const float* __restrict__ b1c,
    const float* __restrict__ W2c, const float* __restrict__ b2c,
    const int* __restrict__ src_vv, const int* __restrict__ dst_vv,
    const int* __restrict__ src_vc, const int* __restrict__ dst_vc,
    unsigned short* __restrict__ table, int* __restrict__ gcur,
    unsigned int* __restrict__ records) {
  __shared__ SMem sm;
  const int q = blockIdx.x / 7;
  const int r = blockIdx.x % 7;
  if (r == 0) {
    fill_block(src_vv, dst_vv, src_vc, dst_vc, gcur, records, q, &sm);
  } else {
    const int mb = q * 6 + (r - 1);
    if (mb >= MLP_B) return;
    if (mb < MLPV_B)
      mlp16(x_v, W1v, b1v, W2v, b2v, table, mb, NN, sm.m.xs, sm.m.hs);
    else
      mlp16(x_c, W1c, b1c, W2c, b2c, table + (size_t)NN * DD, mb - MLPV_B, NC,
            sm.m.xs, sm.m.hs);
  }
}

// ---------------------------------------------------------------------------
// Gather (r12 form): block = 32 vertices (bucket blk>>3, eighth blk&7). ONE
// pass over the bucket's records (uint4-vectorized) places srcs into fixed
// 64-slot per-vertex LDS lists; then 8-lane groups accumulate bf16 table rows
// (8 in flight) + x_v + relu. x_v prefetched early.
// ---------------------------------------------------------------------------
__device__ __forceinline__ void acc8(float* a, const uint4 t) {
  a[0] += __uint_as_float(t.x << 16);
  a[1] += __uint_as_float(t.x & 0xffff0000u);
  a[2] += __uint_as_float(t.y << 16);
  a[3] += __uint_as_float(t.y & 0xffff0000u);
  a[4] += __uint_as_float(t.z << 16);
  a[5] += __uint_as_float(t.z & 0xffff0000u);
  a[6] += __uint_as_float(t.w << 16);
  a[7] += __uint_as_float(t.w & 0xffff0000u);
}

__device__ __forceinline__ void place(unsigned int u, int sub, int* c1,
                                      unsigned short* slots) {
  const int dd = u >> 16;
  if (((dd >> 5) & 7) == sub) {
    const int lv = dd & 31;
    const int pos = atomicAdd(&c1[lv], 1);
    if (pos < VCAP) slots[lv * VCAP + pos] = (unsigned short)(u & 0xffffu);
  }
}

__global__ __launch_bounds__(256) void gather_kernel(
    const uint4* __restrict__ table4, const unsigned int* __restrict__ records,
    const int* __restrict__ gcur, const float4* __restrict__ xv4,
    float4* __restrict__ out4) {
  __shared__ int c1[32];
  __shared__ unsigned short slots[32 * VCAP];  // 4 KB
  const int t = threadIdx.x;
  const int bucket = blockIdx.x >> 3;
  const int sub = blockIdx.x & 7;
  const int start = bucket * BCAP;
  const int nrec = gcur[bucket];

  // early x_v prefetch for this thread's vertex (independent of the scan)
  const int g = t >> 3;
  const int c = t & 7;
  const int v = bucket * 256 + sub * 32 + g;
  const size_t ob = (size_t)v * 16 + c * 2;
  float4 x0 = {0.f, 0.f, 0.f, 0.f}, x1 = x0;
  if (v < NN) {
    x0 = xv4[ob];
    x1 = xv4[ob + 1];
  }

  if (t < 32) c1[t] = 0;
  __syncthreads();

  // single placement pass, uint4-vectorized (records base is 32KB-aligned)
  const uint4* rec4 = (const uint4*)(records + start);
  const int nfull = nrec >> 2;
  for (int q = t; q < nfull; q += 256) {
    const uint4 u = rec4[q];
    place(u.x, sub, c1, slots);
    place(u.y, sub, c1, slots);
    place(u.z, sub, c1, slots);
    place(u.w, sub, c1, slots);
  }
  for (int j = (nfull << 2) + t; j < nrec; j += 256)
    place(records[start + j], sub, c1, slots);
  __syncthreads();

  if (v >= NN) return;
  int n = c1[g];
  n = (n > VCAP) ? VCAP : n;
  const unsigned short* sl = slots + g * VCAP;

  float a[8];
#pragma unroll
  for (int r = 0; r < 8; ++r) a[r] = 0.f;

  int i = 0;
  for (; i + 8 <= n; i += 8) {
    const int e0 = sl[i + 0];
    const int e1 = sl[i + 1];
    const int e2 = sl[i + 2];
    const int e3 = sl[i + 3];
    const int e4 = sl[i + 4];
    const int e5 = sl[i + 5];
    const int e6 = sl[i + 6];
    const int e7 = sl[i + 7];
    const uint4 t0 = table4[(size_t)e0 * 8 + c];
    const uint4 t1 = table4[(size_t)e1 * 8 + c];
    const uint4 t2 = table4[(size_t)e2 * 8 + c];
    const uint4 t3 = table4[(size_t)e3 * 8 + c];
    const uint4 t4 = table4[(size_t)e4 * 8 + c];
    const uint4 t5 = table4[(size_t)e5 * 8 + c];
    const uint4 t6 = table4[(size_t)e6 * 8 + c];
    const uint4 t7 = table4[(size_t)e7 * 8 + c];
    acc8(a, t0); acc8(a, t1); acc8(a, t2); acc8(a, t3);
    acc8(a, t4); acc8(a, t5); acc8(a, t6); acc8(a, t7);
  }
  for (; i + 4 <= n; i += 4) {
    const int e0 = sl[i + 0];
    const int e1 = sl[i + 1];
    const int e2 = sl[i + 2];
    const int e3 = sl[i + 3];
    const uint4 t0 = table4[(size_t)e0 * 8 + c];
    const uint4 t1 = table4[(size_t)e1 * 8 + c];
    const uint4 t2 = table4[(size_t)e2 * 8 + c];
    const uint4 t3 = table4[(size_t)e3 * 8 + c];
    acc8(a, t0); acc8(a, t1); acc8(a, t2); acc8(a, t3);
  }
  for (; i < n; ++i) {
    const uint4 t0 = table4[(size_t)sl[i] * 8 + c];
    acc8(a, t0);
  }

  float4 o0, o1;
  o0.x = fmaxf(x0.x + a[0], 0.f);
  o0.y = fmaxf(x0.y + a[1], 0.f);
  o0.z = fmaxf(x0.z + a[2], 0.f);
  o0.w = fmaxf(x0.w + a[3], 0.f);
  o1.x = fmaxf(x1.x + a[4], 0.f);
  o1.y = fmaxf(x1.y + a[5], 0.f);
  o1.z = fmaxf(x1.z + a[6], 0.f);
  o1.w = fmaxf(x1.w + a[7], 0.f);
  out4[ob] = o0;
  out4[ob + 1] = o1;
}

extern "C" void kernel_launch(void* const* d_in, const int* in_sizes, int n_in,
                              void* d_out, int out_size, void* d_ws,
                              size_t ws_size, hipStream_t stream) {
  const float* x_v = (const float*)d_in[0];
  const float* x_c = (const float*)d_in[1];
  const float* W1v = (const float*)d_in[2];
  const float* b1v = (const float*)d_in[3];
  const float* W2v = (const float*)d_in[4];
  const float* b2v = (const float*)d_in[5];
  const float* W1c = (const float*)d_in[6];
  const float* b1c = (const float*)d_in[7];
  const float* W2c = (const float*)d_in[8];
  const float* b2c = (const float*)d_in[9];
  const int* src_vv = (const int*)d_in[10];
  const int* dst_vv = (const int*)d_in[11];
  const int* src_vc = (const int*)d_in[12];
  const int* dst_vc = (const int*)d_in[13];
  float* out = (float*)d_out;

  // workspace: table(bf16) 6.43 MB | records 6.42 MB | gcur 784 B
  char* p = (char*)d_ws;
  unsigned short* table = (unsigned short*)p;
  p += (size_t)(NN + NC) * DD * sizeof(unsigned short);
  unsigned int* records = (unsigned int*)p;
  p += (size_t)NB * BCAP * sizeof(unsigned int);
  int* gcur = (int*)p;

  hipMemsetAsync(gcur, 0, NB * sizeof(int), stream);

  k1_kernel<<<K1_B, 256, 0, stream>>>(x_v, x_c, W1v, b1v, W2v, b2v, W1c, b1c,
                                      W2c, b2c, src_vv, dst_vv, src_vc, dst_vc,
                                      table, gcur, records);

  gather_kernel<<<GAT_B, 256, 0, stream>>>((const uint4*)table, records, gcur,
                                           (const float4*)x_v, (float4*)out);
}

// Round 15
// 144.224 us; speedup vs baseline: 1.0479x; 1.0459x over previous
//
#include <hip/hip_runtime.h>

#define NN 50000
#define NC 256
#define DD 64
#define HH 128
#define EVV 800000
#define EVC 400000
#define NE 1200000
#define NB 196              // coarse buckets of 256 vertices (d>>8)
#define BCAP 8192           // records per bucket region; mean 6122, +26 sigma
#define MLPV_B 782          // ceil(NN/64)  (64 rows/block, 16/wave via MFMA)
#define MLPC_B 4            // NC/64
#define MLP_B (MLPV_B + MLPC_B)   // 786
#define FILL_EPB 2048
#define FILL_B 586          // ceil(NE/2048)
#define QUADS 197           // ceil(786/4); fill needs ceil(586/3)=196
#define K1_B (QUADS * 7)    // period-7: 3 fill + 4 mlp per septet
#define GAT_B (NB * 8)      // 1568 blocks: 8 sub-blocks x 32 vertices / bucket
#define VCAP 64             // slots per vertex; Poisson(24), P(>64) ~ 1e-11
#define HROW 136            // H-tile row pitch (128 + 8 pad: kills bank conflicts)

typedef __attribute__((ext_vector_type(8))) short bf16x8;
typedef __attribute__((ext_vector_type(4))) float f32x4;

__device__ __forceinline__ unsigned short f2bf(float x) {
  unsigned u = __float_as_uint(x);
  u = (u + 0x7fffu + ((u >> 16) & 1u)) >> 16;  // round-to-nearest-even
  return (unsigned short)u;
}

// LDS overlay: mfma-mlp H tiles (17.4 KB) and fill (~12.6 KB) never coexist.
union SMem {
  unsigned short hl[4][16 * HROW];  // per-wave H tile, 4352 B each
  struct {
    int cnt[NB];
    int off[NB];
    int gbase[NB];
    int sa[256], sb[256];
    unsigned int stage[FILL_EPB];  // 8 KB
  } f;
};

// ---------------------------------------------------------------------------
// Weight prep: one-time transpose+convert to bf16.
// wt layout: W1t_v [128][64] | W2t_v [64][128] | W1t_c | W2t_c  (8192 each)
// W1t[n][k] = bf16(W1[k][n]); W2t[n][k] = bf16(W2[k][n]).
// ---------------------------------------------------------------------------
__global__ __launch_bounds__(256) void prep_kernel(
    const float* __restrict__ W1v, const float* __restrict__ W2v,
    const float* __restrict__ W1c, const float* __restrict__ W2c,
    unsigned short* __restrict__ wt) {
  const int tid = blockIdx.x * 256 + threadIdx.x;  // 0..32767
  const int sel = tid >> 13;
  const int t = tid & 8191;
  unsigned short* dst = wt + sel * 8192;
  if (sel == 0) {
    const int n = t >> 6, k = t & 63;
    dst[t] = f2bf(W1v[k * HH + n]);
  } else if (sel == 1) {
    const int n = t >> 7, k = t & 127;
    dst[t] = f2bf(W2v[k * DD + n]);
  } else if (sel == 2) {
    const int n = t >> 6, k = t & 63;
    dst[t] = f2bf(W1c[k * HH + n]);
  } else {
    const int n = t >> 7, k = t & 127;
    dst[t] = f2bf(W2c[k * DD + n]);
  }
}

// ---------------------------------------------------------------------------
// MFMA MLP, 16 rows per wave (64/block):
//   H[16x128] = relu(X[16x64] @ W1 + b1)   -- 8 ntiles x 2 mfma_16x16x32_bf16
//   O[16x64]  = H @ W2 + b2                -- 4 ntiles x 4 mfma
// Fragment layouts (verified m89/m120): A[m=lane&15][k=quad*8+j],
// B[k=quad*8+j][n=lane&15], C/D col=lane&15 row=quad*4+reg.
// H transposes C->A layout through a wave-private padded LDS tile (no
// barrier: in-wave lgkmcnt ordering suffices -- validated r14).
// Replaces r12's 192 LDS-broadcast reads/wave with 32 ds_write_b16 +
// 4 ds_read_b128 -> un-saturates the per-CU LDS issue pipe.
// ---------------------------------------------------------------------------
__device__ __forceinline__ void mlp_mfma(
    const float* __restrict__ X, const unsigned short* __restrict__ W1t,
    const float* __restrict__ b1, const unsigned short* __restrict__ W2t,
    const float* __restrict__ b2, unsigned short* __restrict__ Y, int blk,
    int nrows, unsigned short* __restrict__ hl) {
  const int lane = threadIdx.x & 63;
  const int m = lane & 15;
  const int quad = lane >> 4;
  const int rowbase = blk * 64 + (threadIdx.x >> 6) * 16;

  // A fragments: X[rowbase+m][quad*8 + j], two K=32 tiles, fp32 -> bf16
  bf16x8 a0, a1;
  {
    float4 xa = {0.f, 0.f, 0.f, 0.f}, xb = xa, xc = xa, xd = xa;
    const int row = rowbase + m;
    if (row < nrows) {
      const float* xp = X + (size_t)row * DD + quad * 8;
      xa = *(const float4*)(xp);
      xb = *(const float4*)(xp + 4);
      xc = *(const float4*)(xp + 32);
      xd = *(const float4*)(xp + 36);
    }
    a0[0] = (short)f2bf(xa.x); a0[1] = (short)f2bf(xa.y);
    a0[2] = (short)f2bf(xa.z); a0[3] = (short)f2bf(xa.w);
    a0[4] = (short)f2bf(xb.x); a0[5] = (short)f2bf(xb.y);
    a0[6] = (short)f2bf(xb.z); a0[7] = (short)f2bf(xb.w);
    a1[0] = (short)f2bf(xc.x); a1[1] = (short)f2bf(xc.y);
    a1[2] = (short)f2bf(xc.z); a1[3] = (short)f2bf(xc.w);
    a1[4] = (short)f2bf(xd.x); a1[5] = (short)f2bf(xd.y);
    a1[6] = (short)f2bf(xd.z); a1[7] = (short)f2bf(xd.w);
  }

  // phase 1: 8 ntiles of H
#pragma unroll
  for (int nt = 0; nt < 8; ++nt) {
    const int n = nt * 16 + m;
    const float bv = b1[n];
    f32x4 acc = {bv, bv, bv, bv};
    const bf16x8 b0 = *(const bf16x8*)(W1t + n * 64 + quad * 8);
    const bf16x8 b1f = *(const bf16x8*)(W1t + n * 64 + 32 + quad * 8);
    acc = __builtin_amdgcn_mfma_f32_16x16x32_bf16(a0, b0, acc, 0, 0, 0);
    acc = __builtin_amdgcn_mfma_f32_16x16x32_bf16(a1, b1f, acc, 0, 0, 0);
#pragma unroll
    for (int r = 0; r < 4; ++r)
      hl[(quad * 4 + r) * HROW + n] = f2bf(fmaxf(acc[r], 0.f));
  }
  // wave-private H tile: no __syncthreads (in-wave LDS ordering)

  // phase 2 A fragments from H
  bf16x8 ha[4];
#pragma unroll
  for (int kc = 0; kc < 4; ++kc)
    ha[kc] = *(const bf16x8*)(hl + m * HROW + kc * 32 + quad * 8);

#pragma unroll
  for (int nt = 0; nt < 4; ++nt) {
    const int n = nt * 16 + m;
    const float bv = b2[n];
    f32x4 acc = {bv, bv, bv, bv};
#pragma unroll
    for (int kc = 0; kc < 4; ++kc) {
      const bf16x8 bw = *(const bf16x8*)(W2t + n * 128 + kc * 32 + quad * 8);
      acc = __builtin_amdgcn_mfma_f32_16x16x32_bf16(ha[kc], bw, acc, 0, 0, 0);
    }
#pragma unroll
    for (int r = 0; r < 4; ++r) {
      const int row = rowbase + quad * 4 + r;
      if (row < nrows) Y[(size_t)row * DD + n] = f2bf(acc[r]);
    }
  }
}

// ---------------------------------------------------------------------------
// Fill branch (r12 form): block-local counting sort into NB coarse buckets;
// ONE global atomic per (block,bucket) reserves a run at bucket*BCAP;
// bucket-ordered copy-out -> coalesced runs. Record = (d<<16)|s.
// ---------------------------------------------------------------------------
__device__ __forceinline__ void fill_block(
    const int* __restrict__ src_vv, const int* __restrict__ dst_vv,
    const int* __restrict__ src_vc, const int* __restrict__ dst_vc,
    int* __restrict__ gcur, unsigned int* __restrict__ records, int blk,
    SMem* sm) {
  const int t = threadIdx.x;
  const int base = blk * FILL_EPB;
  if (t < NB) sm->f.cnt[t] = 0;
  __syncthreads();

  unsigned int rec[8];
  int rk[8];
#pragma unroll
  for (int r = 0; r < 8; ++r) {
    const int e = base + r * 256 + t;
    rk[r] = -1;
    if (e < NE) {
      int s, d;
      if (e < EVV) {
        s = src_vv[e];
        d = dst_vv[e];
      } else {
        s = NN + src_vc[e - EVV];
        d = dst_vc[e - EVV];
      }
      rec[r] = ((unsigned int)d << 16) | (unsigned int)s;
      rk[r] = atomicAdd(&sm->f.cnt[d >> 8], 1);
    }
  }
  __syncthreads();

  const int val = (t < NB) ? sm->f.cnt[t] : 0;
  sm->f.sa[t] = val;
  __syncthreads();
  int* s = sm->f.sa;
  int* d = sm->f.sb;
  for (int o = 1; o < 256; o <<= 1) {
    d[t] = s[t] + ((t >= o) ? s[t - o] : 0);
    __syncthreads();
    int* tmp = s; s = d; d = tmp;
  }
  if (t < NB) {
    sm->f.off[t] = s[t] - val;
    sm->f.gbase[t] = t * BCAP + ((val > 0) ? atomicAdd(&gcur[t], val) : 0);
  }
  __syncthreads();

#pragma unroll
  for (int r = 0; r < 8; ++r)
    if (rk[r] >= 0) sm->f.stage[sm->f.off[rec[r] >> 24] + rk[r]] = rec[r];
  __syncthreads();

  const int total = (NE - base < FILL_EPB) ? (NE - base) : FILL_EPB;
  for (int i = t; i < total; i += 256) {
    const unsigned int u = sm->f.stage[i];
    const int b2 = u >> 24;  // = d >> 8
    records[sm->f.gbase[b2] + (i - sm->f.off[b2])] = u;
  }
}

// ---------------------------------------------------------------------------
// K1 fused, INTERLEAVED period-7: {3 fill, 4 mfma-mlp} per septet.
// ---------------------------------------------------------------------------
__global__ __launch_bounds__(256) void k1_kernel(
    const float* __restrict__ x_v, const float* __restrict__ x_c,
    const float* __restrict__ b1v, const float* __restrict__ b2v,
    const float* __restrict__ b1c, const float* __restrict__ b2c,
    const unsigned short* __restrict__ wt,
    const int* __restrict__ src_vv, const int* __restrict__ dst_vv,
    const int* __restrict__ src_vc, const int* __restrict__ dst_vc,
    unsigned short* __restrict__ table, int* __restrict__ gcur,
    unsigned int* __restrict__ records) {
  __shared__ SMem sm;
  const int q = blockIdx.x / 7;
  const int r = blockIdx.x % 7;
  if (r < 3) {
    const int fid = q * 3 + r;
    if (fid >= FILL_B) return;
    fill_block(src_vv, dst_vv, src_vc, dst_vc, gcur, records, fid, &sm);
  } else {
    const int mb = q * 4 + (r - 3);
    if (mb >= MLP_B) return;
    unsigned short* hl = sm.hl[threadIdx.x >> 6];
    if (mb < MLPV_B)
      mlp_mfma(x_v, wt, b1v, wt + 8192, b2v, table, mb, NN, hl);
    else
      mlp_mfma(x_c, wt + 16384, b1c, wt + 24576, b2c,
               table + (size_t)NN * DD, mb - MLPV_B, NC, hl);
  }
}

// ---------------------------------------------------------------------------
// Gather (r12 form, unchanged): block = 32 vertices. One placement pass ->
// fixed 64-slot per-vertex LDS lists; 8-lane groups accumulate bf16 table
// rows (8 in flight) + x_v + relu. x_v prefetched early.
// ---------------------------------------------------------------------------
__device__ __forceinline__ void acc8(float* a, const uint4 t) {
  a[0] += __uint_as_float(t.x << 16);
  a[1] += __uint_as_float(t.x & 0xffff0000u);
  a[2] += __uint_as_float(t.y << 16);
  a[3] += __uint_as_float(t.y & 0xffff0000u);
  a[4] += __uint_as_float(t.z << 16);
  a[5] += __uint_as_float(t.z & 0xffff0000u);
  a[6] += __uint_as_float(t.w << 16);
  a[7] += __uint_as_float(t.w & 0xffff0000u);
}

__device__ __forceinline__ void place(unsigned int u, int sub, int* c1,
                                      unsigned short* slots) {
  const int dd = u >> 16;
  if (((dd >> 5) & 7) == sub) {
    const int lv = dd & 31;
    const int pos = atomicAdd(&c1[lv], 1);
    if (pos < VCAP) slots[lv * VCAP + pos] = (unsigned short)(u & 0xffffu);
  }
}

__global__ __launch_bounds__(256) void gather_kernel(
    const uint4* __restrict__ table4, const unsigned int* __restrict__ records,
    const int* __restrict__ gcur, const float4* __restrict__ xv4,
    float4* __restrict__ out4) {
  __shared__ int c1[32];
  __shared__ unsigned short slots[32 * VCAP];  // 4 KB
  const int t = threadIdx.x;
  const int bucket = blockIdx.x >> 3;
  const int sub = blockIdx.x & 7;
  const int start = bucket * BCAP;
  const int nrec = gcur[bucket];

  const int g = t >> 3;
  const int c = t & 7;
  const int v = bucket * 256 + sub * 32 + g;
  const size_t ob = (size_t)v * 16 + c * 2;
  float4 x0 = {0.f, 0.f, 0.f, 0.f}, x1 = x0;
  if (v < NN) {
    x0 = xv4[ob];
    x1 = xv4[ob + 1];
  }

  if (t < 32) c1[t] = 0;
  __syncthreads();

  const uint4* rec4 = (const uint4*)(records + start);
  const int nfull = nrec >> 2;
  for (int q = t; q < nfull; q += 256) {
    const uint4 u = rec4[q];
    place(u.x, sub, c1, slots);
    place(u.y, sub, c1, slots);
    place(u.z, sub, c1, slots);
    place(u.w, sub, c1, slots);
  }
  for (int j = (nfull << 2) + t; j < nrec; j += 256)
    place(records[start + j], sub, c1, slots);
  __syncthreads();

  if (v >= NN) return;
  int n = c1[g];
  n = (n > VCAP) ? VCAP : n;
  const unsigned short* sl = slots + g * VCAP;

  float a[8];
#pragma unroll
  for (int r = 0; r < 8; ++r) a[r] = 0.f;

  int i = 0;
  for (; i + 8 <= n; i += 8) {
    const int e0 = sl[i + 0];
    const int e1 = sl[i + 1];
    const int e2 = sl[i + 2];
    const int e3 = sl[i + 3];
    const int e4 = sl[i + 4];
    const int e5 = sl[i + 5];
    const int e6 = sl[i + 6];
    const int e7 = sl[i + 7];
    const uint4 t0 = table4[(size_t)e0 * 8 + c];
    const uint4 t1 = table4[(size_t)e1 * 8 + c];
    const uint4 t2 = table4[(size_t)e2 * 8 + c];
    const uint4 t3 = table4[(size_t)e3 * 8 + c];
    const uint4 t4 = table4[(size_t)e4 * 8 + c];
    const uint4 t5 = table4[(size_t)e5 * 8 + c];
    const uint4 t6 = table4[(size_t)e6 * 8 + c];
    const uint4 t7 = table4[(size_t)e7 * 8 + c];
    acc8(a, t0); acc8(a, t1); acc8(a, t2); acc8(a, t3);
    acc8(a, t4); acc8(a, t5); acc8(a, t6); acc8(a, t7);
  }
  for (; i + 4 <= n; i += 4) {
    const int e0 = sl[i + 0];
    const int e1 = sl[i + 1];
    const int e2 = sl[i + 2];
    const int e3 = sl[i + 3];
    const uint4 t0 = table4[(size_t)e0 * 8 + c];
    const uint4 t1 = table4[(size_t)e1 * 8 + c];
    const uint4 t2 = table4[(size_t)e2 * 8 + c];
    const uint4 t3 = table4[(size_t)e3 * 8 + c];
    acc8(a, t0); acc8(a, t1); acc8(a, t2); acc8(a, t3);
  }
  for (; i < n; ++i) {
    const uint4 t0 = table4[(size_t)sl[i] * 8 + c];
    acc8(a, t0);
  }

  float4 o0, o1;
  o0.x = fmaxf(x0.x + a[0], 0.f);
  o0.y = fmaxf(x0.y + a[1], 0.f);
  o0.z = fmaxf(x0.z + a[2], 0.f);
  o0.w = fmaxf(x0.w + a[3], 0.f);
  o1.x = fmaxf(x1.x + a[4], 0.f);
  o1.y = fmaxf(x1.y + a[5], 0.f);
  o1.z = fmaxf(x1.z + a[6], 0.f);
  o1.w = fmaxf(x1.w + a[7], 0.f);
  out4[ob] = o0;
  out4[ob + 1] = o1;
}

extern "C" void kernel_launch(void* const* d_in, const int* in_sizes, int n_in,
                              void* d_out, int out_size, void* d_ws,
                              size_t ws_size, hipStream_t stream) {
  const float* x_v = (const float*)d_in[0];
  const float* x_c = (const float*)d_in[1];
  const float* W1v = (const float*)d_in[2];
  const float* b1v = (const float*)d_in[3];
  const float* W2v = (const float*)d_in[4];
  const float* b2v = (const float*)d_in[5];
  const float* W1c = (const float*)d_in[6];
  const float* b1c = (const float*)d_in[7];
  const float* W2c = (const float*)d_in[8];
  const float* b2c = (const float*)d_in[9];
  const int* src_vv = (const int*)d_in[10];
  const int* dst_vv = (const int*)d_in[11];
  const int* src_vc = (const int*)d_in[12];
  const int* dst_vc = (const int*)d_in[13];
  float* out = (float*)d_out;

  // workspace: table(bf16) 6.43 MB | records 6.42 MB | wt 64 KB | gcur
  char* p = (char*)d_ws;
  unsigned short* table = (unsigned short*)p;
  p += (size_t)(NN + NC) * DD * sizeof(unsigned short);
  unsigned int* records = (unsigned int*)p;
  p += (size_t)NB * BCAP * sizeof(unsigned int);
  unsigned short* wt = (unsigned short*)p;
  p += (size_t)4 * 8192 * sizeof(unsigned short);
  int* gcur = (int*)p;

  hipMemsetAsync(gcur, 0, NB * sizeof(int), stream);

  prep_kernel<<<128, 256, 0, stream>>>(W1v, W2v, W1c, W2c, wt);

  k1_kernel<<<K1_B, 256, 0, stream>>>(x_v, x_c, b1v, b2v, b1c, b2c, wt,
                                      src_vv, dst_vv, src_vc, dst_vc, table,
                                      gcur, records);

  gather_kernel<<<GAT_B, 256, 0, stream>>>((const uint4*)table, records, gcur,
                                           (const float4*)x_v, (float4*)out);
}